// Round 1
// baseline (26.909 us; speedup 1.0000x reference)
//
#include <hip/hip_runtime.h>

typedef _Float16 half8 __attribute__((ext_vector_type(8)));
typedef float f32x4 __attribute__((ext_vector_type(4)));

#define WPB 4  // waves per block, 1 batch element per wave

__global__ __launch_bounds__(256) void rho_kernel(const float* __restrict__ in,
                                                  float* __restrict__ out,
                                                  int n_batch, int interleaved)
{
    // Per-wave P matrix (16 rows x 32 cols f16), stored column-group-major:
    // P[wave][g][r][8 halves]; fragment read = consecutive 16B per lane -> conflict-free.
    __shared__ __align__(16) ushort P[WPB][4][16][8];

    const int tid  = threadIdx.x;
    const int wave = tid >> 6;
    const int lane = tid & 63;
    int b = blockIdx.x * WPB + wave;
    if (b >= n_batch) b = n_batch - 1;  // clamp (duplicate work, benign) so __syncthreads is safe

    // ---- coalesced load: 4 f32 per lane = full 256-float batch per wave ----
    const float4 v = *reinterpret_cast<const float4*>(in + ((size_t)b << 8) + 4 * lane);

    // ---- zero this wave's P region (1KB): 16B per lane ----
    ushort* pbase = &P[wave][0][0][0];
    *reinterpret_cast<uint4*>(pbase + lane * 8) = make_uint4(0u, 0u, 0u, 0u);

    // ---- convert to f16; trace from the rounded values (consistent with MFMA numerator) ----
    _Float16 h0 = (_Float16)v.x, h1 = (_Float16)v.y, h2 = (_Float16)v.z, h3 = (_Float16)v.w;
    float f0 = (float)h0, f1 = (float)h1, f2 = (float)h2, f3 = (float)h3;
    float tr = f0*f0 + f1*f1 + f2*f2 + f3*f3;

    // ---- scatter into P ----
    // input idx m: m<16 -> diag d_r at P[r][2r]; m>=16 -> c=m-16, row r with r(r-1)<=c<r(r+1),
    // col o = c - r(r-1). LDS ushort offset for (r, col o): (o>>3)*128 + r*8 + (o&7).
    if (lane < 4) {
        _Float16 hs[4] = {h0, h1, h2, h3};
        #pragma unroll
        for (int e = 0; e < 4; ++e) {
            int r = 4 * lane + e;
            int o = 2 * r;
            union { _Float16 h; ushort u; } cv; cv.h = hs[e];
            pbase[(o >> 3) * 128 + r * 8 + (o & 7)] = cv.u;
        }
    } else {
        uint pk[2];
        { union { _Float16 h[2]; uint u; } u0; u0.h[0] = h0; u0.h[1] = h1; pk[0] = u0.u; }
        { union { _Float16 h[2]; uint u; } u1; u1.h[0] = h2; u1.h[1] = h3; pk[1] = u1.u; }
        #pragma unroll
        for (int e = 0; e < 2; ++e) {
            int c = 4 * lane - 16 + 2 * e;                     // even pair offset
            int r = (int)((1.0f + sqrtf((float)(4 * c + 1))) * 0.5f);
            if (r * (r - 1) > c) --r;                          // integer fixups (belt & braces)
            if ((r + 1) * r <= c) ++r;
            int o = c - r * (r - 1);                           // even -> 4B aligned
            *reinterpret_cast<uint*>(pbase + (o >> 3) * 128 + r * 8 + (o & 7)) = pk[e];
        }
    }

    // ---- 64-lane trace reduction ----
    #pragma unroll
    for (int m = 1; m < 64; m <<= 1) tr += __shfl_xor(tr, m, 64);

    __syncthreads();  // LDS scatter visible before fragment reads

    // ---- fragment: lane -> g = lane>>4 (cols 8g..8g+7), r = lane&15 ----
    union { half8 h; uint u[4]; } up, uq;
    up.h = *reinterpret_cast<half8*>(pbase + (lane >> 4) * 128 + (lane & 15) * 8);

    // Q = pairwise (a,b) -> (b,-a): rotate 16 + flip sign of new high half
    #pragma unroll
    for (int m = 0; m < 4; ++m) {
        uint x = up.u[m];
        uq.u[m] = ((x >> 16) | (x << 16)) ^ 0x80000000u;
    }

    f32x4 zero = {0.f, 0.f, 0.f, 0.f};
    f32x4 rre = __builtin_amdgcn_mfma_f32_16x16x32_f16(up.h, up.h, zero, 0, 0, 0); // Re = P P^T
    f32x4 rim = __builtin_amdgcn_mfma_f32_16x16x32_f16(uq.h, up.h, zero, 0, 0, 0); // Im = Q P^T

    const float inv = 1.0f / tr;
    const int j  = lane & 15;          // C/D: col = lane&15
    const int i0 = (lane >> 4) * 4;    //      row = (lane>>4)*4 + reg

    if (interleaved) {
        #pragma unroll
        for (int m = 0; m < 4; ++m) {
            int i = i0 + m;
            float2 val = make_float2(rre[m] * inv, rim[m] * inv);
            *reinterpret_cast<float2*>(out + ((size_t)b * 256 + i * 16 + j) * 2) = val;
        }
    } else {
        #pragma unroll
        for (int m = 0; m < 4; ++m) {
            int i = i0 + m;
            out[(size_t)b * 256 + i * 16 + j] = rre[m] * inv;
        }
    }
}

extern "C" void kernel_launch(void* const* d_in, const int* in_sizes, int n_in,
                              void* d_out, int out_size, void* d_ws, size_t ws_size,
                              hipStream_t stream)
{
    const float* in = (const float*)d_in[0];
    float* out = (float*)d_out;
    const int n_batch = in_sizes[0] / 256;
    const int interleaved = (out_size == n_batch * 512) ? 1 : 0;
    const int blocks = (n_batch + WPB - 1) / WPB;
    rho_kernel<<<blocks, 256, 0, stream>>>(in, out, n_batch, interleaved);
}